// Round 4
// baseline (409.511 us; speedup 1.0000x reference)
//
#include <hip/hip_runtime.h>
#include <stdint.h>

#define Bb 64
#define Hh 128
#define Ww 128
#define Cc 21
#define Pp 49152          // NUM_SAMPLED
#define Kk 36864          // NUM_UNCERTAIN
#define NR 12288          // NUM_RANDOM

#define BINS 2048         // 11-bit digits; pass shifts 16/27/38 (bits >=47 are 0)
#define TILE 4096         // elements per sort tile
#define TILES 12          // Pp / TILE
#define NBLK (Bb * TILES) // 768 sample/scatter blocks

typedef uint32_t u32;
typedef uint64_t u64;
typedef unsigned short u16;

// XCD-affine decode: all TILES blocks of segment s have blk%8 == s%8, so the
// round-robin block->XCD dispatch keeps a segment's 384 KB r/w window in ONE
// XCD's L2 (8 segments x ~770 KB = 6 MB/XCD vs 4 MB L2 -> mostly resident).
// Performance heuristic only; correctness never depends on placement.
#define DECODE_ST const int s = blk & 63; const int t = blk >> 6;

// 11-bit ballot digit-match: mask of lanes in this wave holding digit d.
__device__ __forceinline__ u64 match11(u32 d) {
    u64 m = ~0ull;
    #pragma unroll
    for (int bit = 0; bit < 11; ++bit) {
        u64 bl = __ballot((d >> bit) & 1u);
        m &= ((d >> bit) & 1u) ? bl : ~bl;
    }
    return m;
}

// ---------------------------------------------------------------------------
// Kernel 0: compact channel-0 plane: planes[b][h][w] = logits[b][h][w][0].
// ---------------------------------------------------------------------------
__global__ __launch_bounds__(256) void extract_kernel(const float* __restrict__ logits,
                                                      float* __restrict__ planes) {
    int gid = blockIdx.x * blockDim.x + threadIdx.x;   // [0, B*H*W)
    planes[gid] = logits[(size_t)gid * Cc];
}

// ---------------------------------------------------------------------------
// Kernel 1: bilinear sample (64 KB plane staged in LDS), build sortable key,
// fused pass-0 per-tile histogram. key = fp32 bits of |interp| (order-
// isomorphic for non-negative floats); element = (key << 16) | idx.
// fp contract OFF: the sort permutation feeds the output directly — bit-exact
// numpy arithmetic required (one rank flip = O(1) absmax error).
// ---------------------------------------------------------------------------
__global__ __launch_bounds__(256) void sample_key_kernel(const float* __restrict__ planes,
                                                         const float2* __restrict__ coords,
                                                         u64* __restrict__ keys,
                                                         u32* __restrict__ hist) {
#pragma clang fp contract(off)
    __shared__ float pl[Hh * Ww];      // 64 KB
    __shared__ u32 h[BINS];            // 8 KB
    const int tid = threadIdx.x;
    const int blk = blockIdx.x;
    DECODE_ST

    for (int i = tid; i < BINS; i += 256) h[i] = 0;
    const float4* p4 = (const float4*)(planes + s * (Hh * Ww));
    float4* l4 = (float4*)pl;
    #pragma unroll
    for (int i = 0; i < 16; ++i) l4[i * 256 + tid] = p4[i * 256 + tid];
    __syncthreads();

    #pragma unroll 4
    for (int i = 0; i < 16; ++i) {
        int idx = t * TILE + i * 256 + tid;            // point index within segment
        int gid = s * Pp + idx;
        float2 c = coords[gid];
        float xf = c.x * 127.0f;                       // coords[...,0] -> H axis
        float yf = c.y * 127.0f;                       // coords[...,1] -> W axis
        float x0 = floorf(xf), x1 = ceilf(xf);
        float y0 = floorf(yf), y1 = ceilf(yf);
        float mux = xf - x0;
        float muy = yf - y0;
        int x0i = (int)x0, x1i = (int)x1, y0i = (int)y0, y1i = (int)y1;
        float p1 = pl[x0i * Ww + y0i];
        float p2 = pl[x1i * Ww + y0i];
        float p3 = pl[x0i * Ww + y1i];
        float p4v = pl[x1i * Ww + y1i];
        float p12 = p1 * (1.0f - mux) + p2 * mux;
        float p34 = p3 * (1.0f - mux) + p4v * mux;
        float r   = p12 * (1.0f - muy) + p34 * muy;
        u32 kb = __float_as_uint(r) & 0x7fffffffu;     // |r| bits
        keys[gid] = ((u64)kb << 16) | (u32)idx;
        atomicAdd(&h[kb & (BINS - 1)], 1u);            // pass-0 digit (uniform)
    }
    __syncthreads();
    for (int j = 0; j < 8; ++j) {
        int d = tid * 8 + j;
        hist[((size_t)s * BINS + d) * TILES + t] = h[d];
    }
}

// ---------------------------------------------------------------------------
// Kernel 2 (passes 1,2): fused per-segment histogram + exclusive scan.
// One 1024-thread block per segment: wave w (w<12) builds tile w's digit
// counts alone (ballot-leader u16 updates, race-free: wave w only touches
// column w), then the block scans the 2048x12 table in LDS and writes the
// offset table. Replaces the old hist (768-blk) + scan (64-blk) pair.
// ---------------------------------------------------------------------------
__global__ __launch_bounds__(1024) void hist_scan_kernel(const u64* __restrict__ in,
                                                         u32* __restrict__ off, int shift) {
    __shared__ u16 cnt[BINS * TILES];  // 48 KB, [d][t]
    __shared__ u32 wsum[16];
    const int s = blockIdx.x;
    const int tid = threadIdx.x;
    const int lane = tid & 63;
    const int w = tid >> 6;

    for (int i = tid; i < BINS * TILES / 2; i += 1024) ((u32*)cnt)[i] = 0;
    __syncthreads();

    if (w < TILES) {
        const u64* src = in + (size_t)s * Pp + w * TILE;
        volatile u16* c = cnt;
        for (int i = 0; i < TILE / 64; ++i) {
            u64 v = src[i * 64 + lane];
            u32 d = (u32)(v >> shift) & (BINS - 1);
            u64 m = match11(d);
            if (lane == __ffsll((unsigned long long)m) - 1) {
                u32 p = d * TILES + w;
                c[p] = (u16)(c[p] + (u32)__popcll(m));
            }
        }
    }
    __syncthreads();

    // scan over (d,t) in digit-major order; thread owns digits 2*tid, 2*tid+1
    const int d0 = tid * 2, d1 = tid * 2 + 1;
    u32 c0[TILES], c1[TILES];
    u32 t0 = 0, t1 = 0;
    #pragma unroll
    for (int t = 0; t < TILES; ++t) { c0[t] = cnt[d0 * TILES + t]; t0 += c0[t]; }
    #pragma unroll
    for (int t = 0; t < TILES; ++t) { c1[t] = cnt[d1 * TILES + t]; t1 += c1[t]; }
    u32 ts = t0 + t1;

    u32 sc = ts;
    for (int o = 1; o < 64; o <<= 1) {
        u32 n = __shfl_up(sc, o);
        if (lane >= o) sc += n;
    }
    if (lane == 63) wsum[w] = sc;
    __syncthreads();
    if (tid == 0) {
        u32 run = 0;
        for (int i = 0; i < 16; ++i) { u32 v = wsum[i]; wsum[i] = run; run += v; }
    }
    __syncthreads();
    u32 excl = sc - ts + wsum[w];

    u32* base = off + (size_t)s * BINS * TILES;
    u32 r = excl;
    #pragma unroll
    for (int t = 0; t < TILES; ++t) { base[d0 * TILES + t] = r; r += c0[t]; }
    r = excl + t0;
    #pragma unroll
    for (int t = 0; t < TILES; ++t) { base[d1 * TILES + t] = r; r += c1[t]; }
}

// ---------------------------------------------------------------------------
// Kernel 3 (pass 0 only): per-segment exclusive scan of the sample-built
// per-tile histogram, in place.
// ---------------------------------------------------------------------------
__global__ __launch_bounds__(1024) void scan_kernel(u32* __restrict__ hist) {
    __shared__ u32 wsum[16];
    const int s = blockIdx.x;
    const int tid = threadIdx.x;
    const int lane = tid & 63;
    const int w = tid >> 6;
    u32* base = hist + (size_t)s * BINS * TILES;
    const int d0 = tid * 2, d1 = tid * 2 + 1;

    u32 c0[TILES], c1[TILES];
    u32 t0 = 0, t1 = 0;
    for (int t = 0; t < TILES; ++t) { c0[t] = base[d0 * TILES + t]; t0 += c0[t]; }
    for (int t = 0; t < TILES; ++t) { c1[t] = base[d1 * TILES + t]; t1 += c1[t]; }
    u32 ts = t0 + t1;

    u32 sc = ts;
    for (int o = 1; o < 64; o <<= 1) {
        u32 n = __shfl_up(sc, o);
        if (lane >= o) sc += n;
    }
    if (lane == 63) wsum[w] = sc;
    __syncthreads();
    if (tid == 0) {
        u32 run = 0;
        for (int i = 0; i < 16; ++i) { u32 v = wsum[i]; wsum[i] = run; run += v; }
    }
    __syncthreads();
    u32 excl = sc - ts + wsum[w];

    u32 r = excl;
    for (int t = 0; t < TILES; ++t) { u32 v = c0[t]; base[d0 * TILES + t] = r; r += v; }
    r = excl + t0;
    for (int t = 0; t < TILES; ++t) { u32 v = c1[t]; base[d1 * TILES + t] = r; r += v; }
}

// ---------------------------------------------------------------------------
// Kernel 4: stable scatter with LDS local reorder, then linear read-back and
// run-contiguous global write (gaddr = pos + delta[digit], mod 2^16 exact
// since segment offsets < 49152). Final pass: emit out[s][g] = coords[s][idx]
// directly for g < K.
// ---------------------------------------------------------------------------
__global__ __launch_bounds__(256) void scatter_kernel(const u64* __restrict__ in,
                                                      u64* __restrict__ out_keys,
                                                      const u32* __restrict__ off,
                                                      int shift, int final_pass,
                                                      const float2* __restrict__ coords,
                                                      float2* __restrict__ out) {
    __shared__ u64 el[TILE];           // 32 KB
    __shared__ u16 wh[BINS * 4];       // 16 KB  [digit][wave] counts -> local bases
    __shared__ u16 dl[BINS];           // 4 KB   delta[d] (mod 2^16)
    __shared__ u32 aux[4];
    const int tid = threadIdx.x;
    const int lane = tid & 63;
    const int w = tid >> 6;
    const int blk = blockIdx.x;
    DECODE_ST
    const u64* src = in + (size_t)s * Pp + t * TILE;

    for (int i = tid; i < BINS * 4; i += 256) wh[i] = 0;
    u64 v[16];
    #pragma unroll
    for (int i = 0; i < 16; ++i) v[i] = src[w * 1024 + i * 64 + lane];
    __syncthreads();

    // phase A: per-wave digit histogram (leader-only LDS RMW; wave-lockstep safe)
    volatile u16* vwh = wh;
    for (int i = 0; i < 16; ++i) {
        u32 d = (u32)(v[i] >> shift) & (BINS - 1);
        u64 m = match11(d);
        if (lane == __ffsll((unsigned long long)m) - 1) {
            u32 idx = d * 4 + w;
            vwh[idx] = (u16)(vwh[idx] + (u32)__popcll(m));
        }
    }
    __syncthreads();

    // scan: thread owns 8 digits; local exclusive digit bases + per-wave bases.
    const int d0 = tid * 8;
    u32 dtot[8];
    u32 t8 = 0;
    #pragma unroll
    for (int j = 0; j < 8; ++j) {
        int d = d0 + j;
        u32 c = (u32)wh[d * 4 + 0] + wh[d * 4 + 1] + wh[d * 4 + 2] + wh[d * 4 + 3];
        dtot[j] = c;
        t8 += c;
    }
    u32 sc = t8;
    for (int o = 1; o < 64; o <<= 1) {
        u32 n = __shfl_up(sc, o);
        if (lane >= o) sc += n;
    }
    if (lane == 63) aux[w] = sc;
    __syncthreads();
    if (tid == 0) {
        u32 run = 0;
        for (int i = 0; i < 4; ++i) { u32 x = aux[i]; aux[i] = run; run += x; }
    }
    __syncthreads();
    u32 run = sc - t8 + aux[w];       // exclusive base for this thread's digits
    #pragma unroll
    for (int j = 0; j < 8; ++j) {
        int d = d0 + j;
        u32 ls = run;                 // local_start[d]
        u32 g = off[((size_t)s * BINS + d) * TILES + t];
        dl[d] = (u16)(g - ls);
        u32 c0 = wh[d * 4 + 0], c1 = wh[d * 4 + 1], c2 = wh[d * 4 + 2];
        wh[d * 4 + 0] = (u16)ls;
        wh[d * 4 + 1] = (u16)(ls + c0);
        wh[d * 4 + 2] = (u16)(ls + c0 + c1);
        wh[d * 4 + 3] = (u16)(ls + c0 + c1 + c2);
        run += dtot[j];
    }
    __syncthreads();

    // phase B: stable ballot-ranked scatter into LDS (local sorted order)
    for (int i = 0; i < 16; ++i) {
        u32 d = (u32)(v[i] >> shift) & (BINS - 1);
        u64 m = match11(d);
        u32 before = (u32)__popcll(m & ((1ull << lane) - 1ull));
        u32 base = vwh[d * 4 + w];
        el[base + before] = v[i];
        if (lane == __ffsll((unsigned long long)m) - 1)
            vwh[d * 4 + w] = (u16)(base + (u32)__popcll(m));
    }
    __syncthreads();

    // phase C: linear read-back, run-contiguous global write
    if (!final_pass) {
        u64* dst = out_keys + (size_t)s * Pp;
        for (int i = 0; i < 16; ++i) {
            int pos = i * 256 + tid;
            u64 e = el[pos];
            u32 d = (u32)(e >> shift) & (BINS - 1);
            u32 g = (u32)(u16)(pos + dl[d]);
            dst[g] = e;
        }
    } else {
        const float2* cseg = coords + (size_t)s * Pp;
        float2* oseg = out + (size_t)s * Pp;
        for (int i = 0; i < 16; ++i) {
            int pos = i * 256 + tid;
            u64 e = el[pos];
            u32 d = (u32)(e >> shift) & (BINS - 1);
            u32 g = (u32)(u16)(pos + dl[d]);
            if (g < Kk) {
                u32 idx = (u32)e & 0xffffu;
                oseg[g] = cseg[idx];
            }
        }
    }
}

// ---------------------------------------------------------------------------
// Kernel 5: copy extra_random into rows [K, P) of each segment.
// ---------------------------------------------------------------------------
__global__ __launch_bounds__(256) void extra_copy_kernel(const float2* __restrict__ extra,
                                                         float2* __restrict__ out) {
    int gid = blockIdx.x * blockDim.x + threadIdx.x;   // [0, B*NR)
    int b = gid / NR;
    int j = gid - b * NR;
    out[(size_t)b * Pp + Kk + j] = extra[gid];
}

extern "C" void kernel_launch(void* const* d_in, const int* in_sizes, int n_in,
                              void* d_out, int out_size, void* d_ws, size_t ws_size,
                              hipStream_t stream) {
    const float*  logits = (const float*)d_in[0];   // (B,H,W,C) fp32
    const float2* coords = (const float2*)d_in[1];  // (B,P,2)  fp32
    const float2* extra  = (const float2*)d_in[2];  // (B,NR,2) fp32
    float2* out = (float2*)d_out;

    u64* buf0 = (u64*)d_ws;                          // 25.2 MB
    u64* buf1 = buf0 + (size_t)Bb * Pp;              // 25.2 MB (ping-pong)
    float* planes = (float*)buf1;                    // 4 MB; dead before pass-0 scatter writes buf1
    u32* histA = (u32*)d_out;                        // 6.3 MB scratch (passes 0,1); d_out untouched until final pass
    u32* histB = (u32*)buf1;                         // final-pass offsets in buf1 (dead then)

    extract_kernel<<<(Bb * Hh * Ww) / 256, 256, 0, stream>>>(logits, planes);
    sample_key_kernel<<<NBLK, 256, 0, stream>>>(planes, coords, buf0, histA);

    // pass 0: bits [16,27)  buf0 -> buf1
    scan_kernel<<<Bb, 1024, 0, stream>>>(histA);
    scatter_kernel<<<NBLK, 256, 0, stream>>>(buf0, buf1, histA, 16, 0, nullptr, nullptr);
    // pass 1: bits [27,38)  buf1 -> buf0
    hist_scan_kernel<<<Bb, 1024, 0, stream>>>(buf1, histA, 27);
    scatter_kernel<<<NBLK, 256, 0, stream>>>(buf1, buf0, histA, 27, 0, nullptr, nullptr);
    // pass 2: bits [38,47)  buf0 -> out (fused gather+emit)
    hist_scan_kernel<<<Bb, 1024, 0, stream>>>(buf0, histB, 38);
    scatter_kernel<<<NBLK, 256, 0, stream>>>(buf0, nullptr, histB, 38, 1, coords, out);

    extra_copy_kernel<<<(Bb * NR) / 256, 256, 0, stream>>>(extra, out);
}